// Round 5
// baseline (93.681 us; speedup 1.0000x reference)
//
#include <hip/hip_runtime.h>

// Bilateral 5x5, sigma_spatial=1.5, sigma_color=0.1, reflect pad.
// [2,3,1024,1024] fp32 = 6 independent 1024x1024 images.
//
// Weights via Schraudolph integer-bit exp2 (rel err +/-3%, cancels under
// normalization): tile pre-scaled by Ssc = sqrt(2^23 * 50*log2(e));
//   t = fma(-u,u,Cij), Cij = 2^23*lk2_ij + (127-0.043)*2^23
//   w = bitcast<float>((int)t)     // t>0 always for inputs in [0,1]
// Tap = sub, fma, cvt_i32, add, fma: 5 full-rate VALU ops, no transcendental.
//
// R4: TY=64 (grid 1536 = 6 blocks/CU, all resident in one round; LDS cap 8).
// Staging (global latency + barrier) amortized over 3840 VALU-cyc of compute
// per wave (was ~960 at TY=16 -- staging exposure was the R3 stall).
// Each thread: 16-row column, 2 rows/iter, 6-row register window,
// 4 independent accumulator chains per pixel pair.

#define TX 64
#define TY 64
#define BY 4
#define RPT (TY / BY)     // 16 output rows per thread
#define PAD 2
#define LW (TX + 2 * PAD) // 68
#define LH (TY + 2 * PAD) // 68

__global__ __launch_bounds__(256) void bilateral_kernel(
    const float* __restrict__ in, float* __restrict__ out, int H, int W)
{
    const int z  = blockIdx.z;
    const int x0 = blockIdx.x * TX;
    const int y0 = blockIdx.y * TY;
    const int tx = threadIdx.x;
    const int ty = threadIdx.y;
    const int tid = ty * TX + tx;

    // Ssc = sqrt(2^23 * 50 * log2(e));  SEPS = Ssc * 1e-8
    const float Ssc  = 24598.9869f;
    const float SEPS = 2.45989869e-4f;

    __shared__ float tile[LH * LW];
    const float* img = in + (size_t)z * H * W;

    // Cooperative halo load (reflect, pad=2), pre-scaled by Ssc.
    for (int idx = tid; idx < LH * LW; idx += TX * BY) {
        int r = idx / LW;
        int c = idx - r * LW;
        int gy = y0 - PAD + r;
        int gx = x0 - PAD + c;
        gy = gy < 0 ? -gy : (gy >= H ? 2 * H - 2 - gy : gy);
        gx = gx < 0 ? -gx : (gx >= W ? 2 * W - 2 - gx : gx);
        tile[idx] = img[(size_t)gy * W + gx] * Ssc;
    }
    __syncthreads();

    // log2 of normalized 1-D spatial gaussian (sigma=1.5, k=5).
    constexpr double Ld[5] = {-3.0580100, -2.0962162, -1.7756103,
                              -2.0962162, -3.0580100};
    constexpr double A  = 8388608.0;           // 2^23
    constexpr double C0 = 1064992506.0;        // (127 - 0.043) * 2^23
    const float K2C = 0.0853118f;              // exact center weight k1n[2]^2

    const int ly0 = ty * RPT;                  // first output row (tile coords)

    // 6-row circular register window (scaled values).
    float win[6][5];
#pragma unroll
    for (int r = 0; r < 4; ++r)
#pragma unroll
        for (int j = 0; j < 5; ++j)
            win[r][j] = tile[(ly0 + r) * LW + tx + j];

#pragma unroll
    for (int q = 0; q < RPT; q += 2) {
        // Load the two incoming rows (tile rows ly0+q+4, ly0+q+5).
        const int sA = (q + 4) % 6, sB = (q + 5) % 6;
#pragma unroll
        for (int j = 0; j < 5; ++j)
            win[sA][j] = tile[(ly0 + q + 4) * LW + tx + j];
#pragma unroll
        for (int j = 0; j < 5; ++j)
            win[sB][j] = tile[(ly0 + q + 5) * LW + tx + j];

        const float c0 = win[(q + 2) % 6][2];   // scaled centers
        const float c1 = win[(q + 3) % 6][2];

        float w0a = K2C, v0a = K2C * c0, w0b = 0.f, v0b = 0.f;
        float w1a = K2C, v1a = K2C * c1, w1b = 0.f, v1b = 0.f;

#pragma unroll
        for (int i = 0; i < 5; ++i) {
            const int r0 = (q + i) % 6;         // row i of out0's window
            const int r1 = (q + 1 + i) % 6;     // row i of out1's window
#pragma unroll
            for (int j = 0; j < 5; ++j) {
                if (i == 2 && j == 2) continue; // center handled exactly
                const float Cij = (float)(A * (Ld[i] + Ld[j]) + C0);
                {
                    const float p = win[r0][j];
                    const float u = p - c0;
                    const float t = __builtin_fmaf(-u, u, Cij);
                    const float w = __builtin_bit_cast(float, (int)t);
                    if (((i * 5 + j) & 1) == 0) { w0a += w; v0a = __builtin_fmaf(w, p, v0a); }
                    else                        { w0b += w; v0b = __builtin_fmaf(w, p, v0b); }
                }
                {
                    const float p = win[r1][j];
                    const float u = p - c1;
                    const float t = __builtin_fmaf(-u, u, Cij);
                    const float w = __builtin_bit_cast(float, (int)t);
                    if (((i * 5 + j) & 1) == 0) { w1a += w; v1a = __builtin_fmaf(w, p, v1a); }
                    else                        { w1b += w; v1b = __builtin_fmaf(w, p, v1b); }
                }
            }
        }
        const float w0 = w0a + w0b, v0 = v0a + v0b;
        const float w1 = w1a + w1b, v1 = v1a + v1b;
        const float r0v = __builtin_amdgcn_rcpf(__builtin_fmaf(Ssc, w0, SEPS));
        const float r1v = __builtin_amdgcn_rcpf(__builtin_fmaf(Ssc, w1, SEPS));
        const size_t base = ((size_t)z * H + (y0 + ly0 + q)) * W + (x0 + tx);
        out[base]     = v0 * r0v;
        out[base + W] = v1 * r1v;
    }
}

extern "C" void kernel_launch(void* const* d_in, const int* in_sizes, int n_in,
                              void* d_out, int out_size, void* d_ws, size_t ws_size,
                              hipStream_t stream) {
    const float* img = (const float*)d_in[0];
    float* out = (float*)d_out;

    const int B = 2, C = 3, H = 1024, W = 1024;
    dim3 block(TX, BY, 1);
    dim3 grid(W / TX, H / TY, B * C);   // 16 x 16 x 6 = 1536 blocks
    bilateral_kernel<<<grid, block, 0, stream>>>(img, out, H, W);
}

// Round 6
// 93.240 us; speedup vs baseline: 1.0047x; 1.0047x over previous
//
#include <hip/hip_runtime.h>

// Bilateral 5x5, sigma_spatial=1.5, sigma_color=0.1, reflect pad.
// [2,3,1024,1024] fp32 = 6 independent 1024x1024 images.
//
// Weights w = exp2(x), x = lk2_ij - (p-c)^2 * 50*log2(e), via Schraudolph
// WITHOUT any float->int conversion (v_cvt measured ~half-rate on gfx950):
//   tile pre-scaled by S13 = sqrt(2^13 * 50*log2(e)) = 768.7444
//   t = fma(-u, u, Cij),  Cij = 12582912 + 2^13*(127 - 0.043 + lk2_ij)
//     -> t in [2^23, 2^24): the fma's rounding IS round-to-int (ulp=1),
//        bits(t) = 0x4B400000 + T, T = (127 - sigma + x)*2^13 in (0, 2^22)
//   w = bitcast<float>(bits(t) << 10)   // magic bits shift out exactly
// Tap = sub, fma, lshl, add, fmac: 5 full-rate VALU ops.
// Never underflows: x >= -78.2 for inputs in [0,1].
//
// Block (64,4): 64x64 tile (grid 1536 = 6 blocks/CU, single round).
// Each thread: 16-row column, 2 rows/iter, 6-row register window,
// 4 independent accumulator chains per pixel.

#define TX 64
#define TY 64
#define BY 4
#define RPT (TY / BY)     // 16 output rows per thread
#define PAD 2
#define LW (TX + 2 * PAD) // 68
#define LH (TY + 2 * PAD) // 68

__global__ __launch_bounds__(256) void bilateral_kernel(
    const float* __restrict__ in, float* __restrict__ out, int H, int W)
{
    const int z  = blockIdx.z;
    const int x0 = blockIdx.x * TX;
    const int y0 = blockIdx.y * TY;
    const int tx = threadIdx.x;
    const int ty = threadIdx.y;
    const int tid = ty * TX + tx;

    // S13 = sqrt(2^13 * 50 * log2(e));  SEPS = S13 * 1e-8
    const float S13  = 768.744433f;
    const float SEPS = 7.68744433e-6f;

    __shared__ float tile[LH * LW];
    const float* img = in + (size_t)z * H * W;

    // Cooperative halo load (reflect, pad=2), pre-scaled by S13.
    for (int idx = tid; idx < LH * LW; idx += TX * BY) {
        int r = idx / LW;
        int c = idx - r * LW;
        int gy = y0 - PAD + r;
        int gx = x0 - PAD + c;
        gy = gy < 0 ? -gy : (gy >= H ? 2 * H - 2 - gy : gy);
        gx = gx < 0 ? -gx : (gx >= W ? 2 * W - 2 - gx : gx);
        tile[idx] = img[(size_t)gy * W + gx] * S13;
    }
    __syncthreads();

    // log2 of normalized 1-D spatial gaussian (sigma=1.5, k=5).
    constexpr double Ld[5] = {-3.0580100, -2.0962162, -1.7756103,
                              -2.0962162, -3.0580100};
    constexpr double A13   = 8192.0;               // 2^13
    constexpr double CMAG  = 12582912.0 + (127.0 - 0.043) * 8192.0;
    const float K2C = 0.0853118f;                  // exact center weight

    const int ly0 = ty * RPT;                      // first output row

    // 6-row circular register window (scaled values).
    float win[6][5];
#pragma unroll
    for (int r = 0; r < 4; ++r)
#pragma unroll
        for (int j = 0; j < 5; ++j)
            win[r][j] = tile[(ly0 + r) * LW + tx + j];

#pragma unroll
    for (int q = 0; q < RPT; q += 2) {
        // Load the two incoming rows (tile rows ly0+q+4, ly0+q+5).
        const int sA = (q + 4) % 6, sB = (q + 5) % 6;
#pragma unroll
        for (int j = 0; j < 5; ++j)
            win[sA][j] = tile[(ly0 + q + 4) * LW + tx + j];
#pragma unroll
        for (int j = 0; j < 5; ++j)
            win[sB][j] = tile[(ly0 + q + 5) * LW + tx + j];

        const float c0 = win[(q + 2) % 6][2];   // scaled centers
        const float c1 = win[(q + 3) % 6][2];

        float w0a = K2C, v0a = K2C * c0, w0b = 0.f, v0b = 0.f;
        float w1a = K2C, v1a = K2C * c1, w1b = 0.f, v1b = 0.f;

#pragma unroll
        for (int i = 0; i < 5; ++i) {
            const int r0 = (q + i) % 6;         // row i of out0's window
            const int r1 = (q + 1 + i) % 6;     // row i of out1's window
#pragma unroll
            for (int j = 0; j < 5; ++j) {
                if (i == 2 && j == 2) continue; // center handled exactly
                const float Cij = (float)(CMAG + A13 * (Ld[i] + Ld[j]));
                {
                    const float p = win[r0][j];
                    const float u = p - c0;
                    const float t = __builtin_fmaf(-u, u, Cij);
                    const float w = __builtin_bit_cast(
                        float, __builtin_bit_cast(int, t) << 10);
                    if (((i * 5 + j) & 1) == 0) { w0a += w; v0a = __builtin_fmaf(w, p, v0a); }
                    else                        { w0b += w; v0b = __builtin_fmaf(w, p, v0b); }
                }
                {
                    const float p = win[r1][j];
                    const float u = p - c1;
                    const float t = __builtin_fmaf(-u, u, Cij);
                    const float w = __builtin_bit_cast(
                        float, __builtin_bit_cast(int, t) << 10);
                    if (((i * 5 + j) & 1) == 0) { w1a += w; v1a = __builtin_fmaf(w, p, v1a); }
                    else                        { w1b += w; v1b = __builtin_fmaf(w, p, v1b); }
                }
            }
        }
        const float w0 = w0a + w0b, v0 = v0a + v0b;
        const float w1 = w1a + w1b, v1 = v1a + v1b;
        const float r0v = __builtin_amdgcn_rcpf(__builtin_fmaf(S13, w0, SEPS));
        const float r1v = __builtin_amdgcn_rcpf(__builtin_fmaf(S13, w1, SEPS));
        const size_t base = ((size_t)z * H + (y0 + ly0 + q)) * W + (x0 + tx);
        out[base]     = v0 * r0v;
        out[base + W] = v1 * r1v;
    }
}

extern "C" void kernel_launch(void* const* d_in, const int* in_sizes, int n_in,
                              void* d_out, int out_size, void* d_ws, size_t ws_size,
                              hipStream_t stream) {
    const float* img = (const float*)d_in[0];
    float* out = (float*)d_out;

    const int B = 2, C = 3, H = 1024, W = 1024;
    dim3 block(TX, BY, 1);
    dim3 grid(W / TX, H / TY, B * C);   // 16 x 16 x 6 = 1536 blocks
    bilateral_kernel<<<grid, block, 0, stream>>>(img, out, H, W);
}

// Round 7
// 91.834 us; speedup vs baseline: 1.0201x; 1.0153x over previous
//
#include <hip/hip_runtime.h>

// Bilateral 5x5, sigma_spatial=1.5, sigma_color=0.1, reflect pad.
// [2,3,1024,1024] fp32 = 6 independent 1024x1024 images.
//
// Schraudolph magic-window weights (no cvt, no transcendental):
//   tile pre-scaled by S13 = sqrt(2^13*50*log2(e));
//   t = fma(-u,u,Cij), Cij = 12582912 + 2^13*(127-0.043+lk2_ij)
//   t in [2^23,2^24): bits(t) = 0x4B400000 + s; w = bitcast(bits<<10).
// R6: taps packed in float2 along j ({0,1},{2,3} pairs + scalar j=4):
//   v_pk_add/fma_f32 for sub/fma/accumulate, and ONE v_lshlrev_b64
//   decodes BOTH packed weights (high word gains +0x12D in low mantissa
//   bits = +3.6e-5 rel, negligible). 5 instr per 2 taps vs 10 scalar.
// Center tap (2,2) rides the packed pipe approximately; exact value
// restored via constant accumulator-init bias CORR = K2C - W22.
//
// Block (64,4): 64x64 tile, grid 1536 = 6 blocks/CU uniform.

#define TX 64
#define TY 64
#define BY 4
#define RPT (TY / BY)     // 16 output rows per thread
#define PAD 2
#define LW (TX + 2 * PAD) // 68
#define LH (TY + 2 * PAD) // 68

typedef float f2 __attribute__((ext_vector_type(2)));

__device__ __forceinline__ f2 decode2(f2 t) {
    unsigned long long b = __builtin_bit_cast(unsigned long long, t);
    return __builtin_bit_cast(f2, b << 10);
}
__device__ __forceinline__ float decode1(float t) {
    return __builtin_bit_cast(float, __builtin_bit_cast(unsigned, t) << 10);
}

__global__ __launch_bounds__(256) void bilateral_kernel(
    const float* __restrict__ in, float* __restrict__ out, int H, int W)
{
    const int z  = blockIdx.z;
    const int x0 = blockIdx.x * TX;
    const int y0 = blockIdx.y * TY;
    const int tx = threadIdx.x;
    const int ty = threadIdx.y;
    const int tid = ty * TX + tx;

    // S13 = sqrt(2^13 * 50 * log2(e));  SEPS = S13 * 1e-8
    const float S13  = 768.744433f;
    const float SEPS = 7.68744433e-6f;

    __shared__ float tile[LH * LW];
    const float* img = in + (size_t)z * H * W;

    // Cooperative halo load (reflect, pad=2), pre-scaled by S13.
    for (int idx = tid; idx < LH * LW; idx += TX * BY) {
        int r = idx / LW;
        int c = idx - r * LW;
        int gy = y0 - PAD + r;
        int gx = x0 - PAD + c;
        gy = gy < 0 ? -gy : (gy >= H ? 2 * H - 2 - gy : gy);
        gx = gx < 0 ? -gx : (gx >= W ? 2 * W - 2 - gx : gx);
        tile[idx] = img[(size_t)gy * W + gx] * S13;
    }
    __syncthreads();

    // log2 of normalized 1-D spatial gaussian (sigma=1.5, k=5).
    constexpr double Ld[5] = {-3.0580100, -2.0962162, -1.7756103,
                              -2.0962162, -3.0580100};
    constexpr double A13   = 8192.0;               // 2^13
    constexpr double CMAG  = 12582912.0 + (127.0 - 0.043) * 8192.0;
#define CD(i, j) ((float)(CMAG + A13 * (Ld[i] + Ld[j])))

    const float K2C  = 0.0853118f;                 // exact center weight
    const float W22  = decode1(CD(2, 2));          // schraudolph center (folds)
    const float CORR = K2C - W22;                  // accumulator-init bias

    const int ly0 = ty * RPT;

    // 6-row circular register window as j-pairs:
    // wA = cols {tx,tx+1} (j=0,1), wB = {tx+2,tx+3} (j=2,3), wC = tx+4 (j=4).
    f2    wA[6], wB[6];
    float wC[6];
#pragma unroll
    for (int r = 0; r < 4; ++r) {
        const int o = (ly0 + r) * LW + tx;
        wA[r] = f2{tile[o],     tile[o + 1]};
        wB[r] = f2{tile[o + 2], tile[o + 3]};
        wC[r] = tile[o + 4];
    }

#pragma unroll
    for (int q = 0; q < RPT; q += 2) {
        // Slide in the two incoming rows (tile rows ly0+q+4, ly0+q+5).
        const int sA = (q + 4) % 6, sB = (q + 5) % 6;
        {
            const int o = (ly0 + q + 4) * LW + tx;
            wA[sA] = f2{tile[o], tile[o + 1]};
            wB[sA] = f2{tile[o + 2], tile[o + 3]};
            wC[sA] = tile[o + 4];
        }
        {
            const int o = (ly0 + q + 5) * LW + tx;
            wA[sB] = f2{tile[o], tile[o + 1]};
            wB[sB] = f2{tile[o + 2], tile[o + 3]};
            wC[sB] = tile[o + 4];
        }

        const float c0 = wB[(q + 2) % 6].x;     // scaled centers (col j=2)
        const float c1 = wB[(q + 3) % 6].x;

        f2 ws0 = f2{CORR, 0.f},      vs0 = f2{CORR * c0, 0.f};
        f2 ws1 = f2{CORR, 0.f},      vs1 = f2{CORR * c1, 0.f};
        float wt0 = 0.f, vt0 = 0.f, wt1 = 0.f, vt1 = 0.f;

#pragma unroll
        for (int i = 0; i < 5; ++i) {
            const int r0 = (q + i) % 6;
            const int r1 = (q + 1 + i) % 6;
            const f2 CA = f2{CD(i, 0), CD(i, 1)};
            const f2 CB = f2{CD(i, 2), CD(i, 3)};
            const float C4 = CD(i, 4);
            // ---- pixel 0 ----
            {
                const f2 c2 = f2{c0, c0};
                f2 u = wA[r0] - c2;
                f2 w = decode2(__builtin_elementwise_fma(-u, u, CA));
                ws0 += w; vs0 = __builtin_elementwise_fma(w, wA[r0], vs0);
                u = wB[r0] - c2;
                w = decode2(__builtin_elementwise_fma(-u, u, CB));
                ws0 += w; vs0 = __builtin_elementwise_fma(w, wB[r0], vs0);
                const float us = wC[r0] - c0;
                const float wsc = decode1(__builtin_fmaf(-us, us, C4));
                wt0 += wsc; vt0 = __builtin_fmaf(wsc, wC[r0], vt0);
            }
            // ---- pixel 1 ----
            {
                const f2 c2 = f2{c1, c1};
                f2 u = wA[r1] - c2;
                f2 w = decode2(__builtin_elementwise_fma(-u, u, CA));
                ws1 += w; vs1 = __builtin_elementwise_fma(w, wA[r1], vs1);
                u = wB[r1] - c2;
                w = decode2(__builtin_elementwise_fma(-u, u, CB));
                ws1 += w; vs1 = __builtin_elementwise_fma(w, wB[r1], vs1);
                const float us = wC[r1] - c1;
                const float wsc = decode1(__builtin_fmaf(-us, us, C4));
                wt1 += wsc; vt1 = __builtin_fmaf(wsc, wC[r1], vt1);
            }
        }
        const float w0 = (ws0.x + ws0.y) + (wt0);
        const float v0 = (vs0.x + vs0.y) + (vt0);
        const float w1 = (ws1.x + ws1.y) + (wt1);
        const float v1 = (vs1.x + vs1.y) + (vt1);
        const float r0v = __builtin_amdgcn_rcpf(__builtin_fmaf(S13, w0, SEPS));
        const float r1v = __builtin_amdgcn_rcpf(__builtin_fmaf(S13, w1, SEPS));
        const size_t base = ((size_t)z * H + (y0 + ly0 + q)) * W + (x0 + tx);
        out[base]     = v0 * r0v;
        out[base + W] = v1 * r1v;
    }
#undef CD
}

extern "C" void kernel_launch(void* const* d_in, const int* in_sizes, int n_in,
                              void* d_out, int out_size, void* d_ws, size_t ws_size,
                              hipStream_t stream) {
    const float* img = (const float*)d_in[0];
    float* out = (float*)d_out;

    const int B = 2, C = 3, H = 1024, W = 1024;
    dim3 block(TX, BY, 1);
    dim3 grid(W / TX, H / TY, B * C);   // 16 x 16 x 6 = 1536 blocks
    bilateral_kernel<<<grid, block, 0, stream>>>(img, out, H, W);
}